// Round 5
// baseline (44.533 us; speedup 1.0000x reference)
//
#include <hip/hip_runtime.h>
#include <hip/hip_bf16.h>
#include <math.h>

// v4: barrier-free fused MLP.
//  - prep_pack: weights fp32 -> bf16 in MFMA-fragment order (lane-major 1KB
//    fragments) in d_ws. B-frag loads in main kernel are global_load_dwordx4
//    at base + lane*16 -- perfectly coalesced, L1-cached across waves.
//  - main kernel: ZERO __syncthreads. Each wave owns 16 batch rows and the
//    FULL N of every layer. Layer-boundary transpose (D-layout -> A-layout)
//    via wave-private 8KB LDS region (same-wave DS ordering, no sync).
//  - x loaded global->reg (fp32, cvt_pk to bf16 in reg), 1 tile ahead;
//    w1 B-frags double-buffered (bA/bB) -> ~10 loads in flight per wave.
// 256 thr (4 indep waves), grid 512, LDS 32KB, launch_bounds(256,2).

#define TPB 256

// packed-weight offsets (shorts): w1p [25kt][8nf][64lane][8], w2p [4][16][64][8], w3p [8][1][64][8]
#define W2P 102400     // 200*512
#define W3P 135168     // 264*512
#define NFRAG_TOT 272  // 200 + 64 + 8
#define WTOT (NFRAG_TOT * 512)

typedef __attribute__((ext_vector_type(8))) short bf16x8;
typedef __attribute__((ext_vector_type(4))) float f32x4;

static __device__ inline short f2bf(float f) {
    union { float f; unsigned u; } v; v.f = f;
    unsigned r = v.u + 0x7fffu + ((v.u >> 16) & 1u);   // RNE
    return (short)(r >> 16);
}
static __device__ inline bf16x8 cvt8(float4 a, float4 b) {
    union { __hip_bfloat162 h2[4]; bf16x8 v; } u;
    u.h2[0] = __float22bfloat162_rn(make_float2(a.x, a.y));
    u.h2[1] = __float22bfloat162_rn(make_float2(a.z, a.w));
    u.h2[2] = __float22bfloat162_rn(make_float2(b.x, b.y));
    u.h2[3] = __float22bfloat162_rn(make_float2(b.z, b.w));
    return u.v;
}
static __device__ inline float4 ld4g(const float* p, bool ok) {
    return ok ? *reinterpret_cast<const float4*>(p) : make_float4(0.f,0.f,0.f,0.f);
}

__global__ void prep_pack(const float* __restrict__ w1,
                          const float* __restrict__ w2,
                          const float* __restrict__ w3,
                          short* __restrict__ wb) {
    const int tid = blockIdx.x * blockDim.x + threadIdx.x;   // one per (frag, lane)
    if (tid >= NFRAG_TOT * 64) return;
    const int fg = tid >> 6, lane = tid & 63;
    const int l15 = lane & 15, l4 = lane >> 4;
    float4 va = make_float4(0,0,0,0), vb = va;
    if (fg < 200) {                       // w1: kt = fg>>3, nf = fg&7
        const int kt = fg >> 3, nf = fg & 7;
        const int kg = kt * 32 + l4 * 8;
        if (kg + 8 <= 784) {
            const float* p = &w1[(size_t)(nf * 16 + l15) * 784 + kg];
            va = *(const float4*)p; vb = *(const float4*)(p + 4);
        }
    } else if (fg < 264) {                // w2: 4 kt x 16 nf
        const int g = fg - 200, kt = g >> 4, nf = g & 15;
        const float* p = &w2[(size_t)(nf * 16 + l15) * 128 + kt * 32 + l4 * 8];
        va = *(const float4*)p; vb = *(const float4*)(p + 4);
    } else {                              // w3: 8 kt, classes on l15 (>=10 zero)
        const int kt = fg - 264;
        if (l15 < 10) {
            const float* p = &w3[(size_t)l15 * 256 + kt * 32 + l4 * 8];
            va = *(const float4*)p; vb = *(const float4*)(p + 4);
        }
    }
    *(bf16x8*)&wb[(size_t)tid * 8] = cvt8(va, vb);
}

__global__ __launch_bounds__(TPB, 2) void mnist_v4(
    const float* __restrict__ x,    // [32768,784]
    const float* __restrict__ b1v,  // [128]
    const float* __restrict__ b2v,  // [256]
    const float* __restrict__ b3v,  // [10]
    const short* __restrict__ wb,   // packed bf16 weights
    float* __restrict__ out)        // [32768,10]
{
    __shared__ __align__(16) short s_h[4][4096];   // 8KB per wave: h1 [16][128] then h2 [16][256] overlay

    const int t    = threadIdx.x;
    const int lane = t & 63;
    const int wv   = t >> 6;
    const int l15  = lane & 15;
    const int l4   = lane >> 4;
    const int r0   = blockIdx.x * 64 + wv * 16;
    short* const hreg = &s_h[wv][0];

    const float* xrow = &x[(size_t)(r0 + l15) * 784];
    const short* w1p = wb;

    // ================= Layer 1: 25 K-tiles of 32, full N=128 per wave =========
    f32x4 acc1[8];
    #pragma unroll
    for (int nf = 0; nf < 8; ++nf) acc1[nf] = (f32x4){0.f,0.f,0.f,0.f};

    bf16x8 bA[8], bB[8];
    #pragma unroll
    for (int nf = 0; nf < 8; ++nf)
        bA[nf] = *(const bf16x8*)&w1p[(0 * 8 + nf) * 512 + lane * 8];
    float4 xc0 = *(const float4*)(xrow + l4 * 8);
    float4 xc1 = *(const float4*)(xrow + l4 * 8 + 4);

    for (int kt = 0; kt < 24; kt += 2) {
        // prefetch tile kt+1 (B->bB, x->xn); kt+1 <= 23 so x always in-bounds
        #pragma unroll
        for (int nf = 0; nf < 8; ++nf)
            bB[nf] = *(const bf16x8*)&w1p[((kt + 1) * 8 + nf) * 512 + lane * 8];
        int kg = (kt + 1) * 32 + l4 * 8;
        float4 xn0 = *(const float4*)(xrow + kg);
        float4 xn1 = *(const float4*)(xrow + kg + 4);
        {
            const bf16x8 a = cvt8(xc0, xc1);
            #pragma unroll
            for (int nf = 0; nf < 8; ++nf)
                acc1[nf] = __builtin_amdgcn_mfma_f32_16x16x32_bf16(a, bA[nf], acc1[nf], 0, 0, 0);
        }
        xc0 = xn0; xc1 = xn1;
        // prefetch tile kt+2 (B->bA, x->xn); kt+2 == 24 is the zero-padded tail
        #pragma unroll
        for (int nf = 0; nf < 8; ++nf)
            bA[nf] = *(const bf16x8*)&w1p[((kt + 2) * 8 + nf) * 512 + lane * 8];
        kg = (kt + 2) * 32 + l4 * 8;
        const bool ok = (kg + 8) <= 784;
        xn0 = ld4g(xrow + kg, ok);
        xn1 = ld4g(xrow + kg + 4, ok);
        {
            const bf16x8 a = cvt8(xc0, xc1);
            #pragma unroll
            for (int nf = 0; nf < 8; ++nf)
                acc1[nf] = __builtin_amdgcn_mfma_f32_16x16x32_bf16(a, bB[nf], acc1[nf], 0, 0, 0);
        }
        xc0 = xn0; xc1 = xn1;
    }
    {   // tail: tile 24 in bA
        const bf16x8 a = cvt8(xc0, xc1);
        #pragma unroll
        for (int nf = 0; nf < 8; ++nf)
            acc1[nf] = __builtin_amdgcn_mfma_f32_16x16x32_bf16(a, bA[nf], acc1[nf], 0, 0, 0);
    }

    // L1 epilogue: bias+relu -> wave-private h1 [16][128] (XOR-swizzled slots)
    #pragma unroll
    for (int nf = 0; nf < 8; ++nf) {
        const int c = nf * 16 + l15;
        const float bc = b1v[c];
        #pragma unroll
        for (int i = 0; i < 4; ++i) {
            const int r = l4 * 4 + i;
            const float h = fmaxf(acc1[nf][i] + bc, 0.f);
            hreg[r * 128 + (((c >> 3) ^ (r & 7)) << 3) + (c & 7)] = f2bf(h);
        }
    }
    // A-frags for layer 2 (row = l15) -- same-wave DS ordering, no barrier
    bf16x8 a2[4];
    #pragma unroll
    for (int kk = 0; kk < 4; ++kk)
        a2[kk] = *(const bf16x8*)&hreg[l15 * 128 + (((kk * 4 + l4) ^ (l15 & 7)) << 3)];

    // ================= Layer 2: 4 K-tiles, full N=256 per wave ================
    f32x4 acc2[16];
    #pragma unroll
    for (int nf = 0; nf < 16; ++nf) acc2[nf] = (f32x4){0.f,0.f,0.f,0.f};
    const short* w2p = wb + W2P;
    #pragma unroll
    for (int kt = 0; kt < 4; ++kt) {
        bf16x8 b2r[16];
        #pragma unroll
        for (int nf = 0; nf < 16; ++nf)
            b2r[nf] = *(const bf16x8*)&w2p[(kt * 16 + nf) * 512 + lane * 8];
        #pragma unroll
        for (int nf = 0; nf < 16; ++nf)
            acc2[nf] = __builtin_amdgcn_mfma_f32_16x16x32_bf16(a2[kt], b2r[nf], acc2[nf], 0, 0, 0);
    }

    // L2 epilogue: bias+relu -> h2 [16][256] (overlays h1; a2 already consumed)
    #pragma unroll
    for (int nf = 0; nf < 16; ++nf) {
        const int c = nf * 16 + l15;
        const float bc = b2v[c];
        #pragma unroll
        for (int i = 0; i < 4; ++i) {
            const int r = l4 * 4 + i;
            const float h = fmaxf(acc2[nf][i] + bc, 0.f);
            hreg[r * 256 + (((c >> 3) ^ (r & 7)) << 3) + (c & 7)] = f2bf(h);
        }
    }

    // ================= Layer 3: 8 K-tiles, N=16 (classes, >=10 zero) ==========
    const short* w3p = wb + W3P;
    f32x4 acc3 = (f32x4){0.f,0.f,0.f,0.f};
    #pragma unroll
    for (int kt = 0; kt < 8; ++kt) {
        const bf16x8 a3 = *(const bf16x8*)&hreg[l15 * 256 + (((kt * 4 + l4) ^ (l15 & 7)) << 3)];
        const bf16x8 b3r = *(const bf16x8*)&w3p[kt * 512 + lane * 8];
        acc3 = __builtin_amdgcn_mfma_f32_16x16x32_bf16(a3, b3r, acc3, 0, 0, 0);
    }

    // bias + log_softmax + store; lane holds logits[r0 + l4*4+i][class=l15]
    const float b3c = (l15 < 10) ? b3v[l15] : 0.f;
    #pragma unroll
    for (int i = 0; i < 4; ++i) {
        const float v = acc3[i] + b3c;
        float m = (l15 < 10) ? v : -1e30f;
        #pragma unroll
        for (int off = 8; off; off >>= 1) m = fmaxf(m, __shfl_xor(m, off, 16));
        const float e = (l15 < 10) ? expf(v - m) : 0.f;
        float sum = e;
        #pragma unroll
        for (int off = 8; off; off >>= 1) sum += __shfl_xor(sum, off, 16);
        const float ls = m + logf(sum);
        if (l15 < 10) {
            const int r = r0 + l4 * 4 + i;
            out[(size_t)r * 10 + l15] = v - ls;
        }
    }
}

extern "C" void kernel_launch(void* const* d_in, const int* in_sizes, int n_in,
                              void* d_out, int out_size, void* d_ws, size_t ws_size,
                              hipStream_t stream) {
    const float* x  = (const float*)d_in[0];
    const float* w1 = (const float*)d_in[1];
    const float* b1 = (const float*)d_in[2];
    const float* w2 = (const float*)d_in[3];
    const float* b2 = (const float*)d_in[4];
    const float* w3 = (const float*)d_in[5];
    const float* b3 = (const float*)d_in[6];
    float* out = (float*)d_out;
    short* wb  = (short*)d_ws;   // needs WTOT*2 = 272KB scratch

    prep_pack<<<(NFRAG_TOT * 64 + TPB - 1) / TPB, TPB, 0, stream>>>(w1, w2, w3, wb);

    dim3 grid(32768 / 64), block(TPB);
    mnist_v4<<<grid, block, 0, stream>>>(x, b1, b2, b3, wb, out);
}